// Round 1
// baseline (65.641 us; speedup 1.0000x reference)
//
#include <hip/hip_runtime.h>

// BilateralSliceApply: grid [4,12,8,16,16] f32, guide [4,1024,1024] f32,
// image [4,3,1024,1024] f32 -> out [4,3,1024,1024] f32.
// Strategy: pre-transpose grid to [B][GH][GW][D][C] (channels contiguous, c=12)
// so each trilinear corner is 3x float4 loads; main kernel is 1 thread/pixel.

static constexpr int BB = 4, CC = 12, DD = 8, GHH = 16, GWW = 16;
static constexpr int HH = 1024, WW = 1024;
static constexpr int HWP = HH * WW;
static constexpr int GRID_N = BB * CC * DD * GHH * GWW;   // 98304 elements

__global__ __launch_bounds__(256) void grid_transpose_k(const float* __restrict__ g,
                                                         float* __restrict__ t) {
    int i = blockIdx.x * 256 + threadIdx.x;
    if (i >= GRID_N) return;
    // input layout [B][C][D][GH][GW]
    int x = i & (GWW - 1);
    int y = (i >> 4) & (GHH - 1);
    int z = (i >> 8) & (DD - 1);
    int c = (i >> 11) % CC;
    int b = i / (CC * DD * GHH * GWW);
    // output layout [B][GH][GW][D][C]
    int o = (((b * GHH + y) * GWW + x) * DD + z) * CC + c;
    t[o] = g[i];
}

template <bool TR>
__global__ __launch_bounds__(256) void bilateral_slice_apply_k(
    const float* __restrict__ grid,   // TR: [B][GH][GW][D][C]; else original layout
    const float* __restrict__ guide,  // [B][H][W]
    const float* __restrict__ image,  // [B][3][H][W]
    float* __restrict__ out)          // [B][3][H][W]
{
    int pid = blockIdx.x * 256 + threadIdx.x;
    if (pid >= BB * HWP) return;
    int sp = pid & (HWP - 1);
    int x = pid & (WW - 1);
    int y = (pid >> 10) & (HH - 1);
    int b = pid >> 20;

    float gx = (x + 0.5f) * ((float)GWW / (float)WW) - 0.5f;
    float gy = (y + 0.5f) * ((float)GHH / (float)HH) - 0.5f;
    float gz = guide[pid] * (float)DD - 0.5f;

    float fx = floorf(gx), fy = floorf(gy), fz = floorf(gz);
    float tx = gx - fx, ty = gy - fy, tz = gz - fz;

    int ix0 = (int)fx, iy0 = (int)fy, iz0 = (int)fz;
    int x0 = min(max(ix0, 0), GWW - 1);
    int x1 = min(max(ix0 + 1, 0), GWW - 1);
    int y0 = min(max(iy0, 0), GHH - 1);
    int y1 = min(max(iy0 + 1, 0), GHH - 1);
    int z0 = min(max(iz0, 0), DD - 1);
    int z1 = min(max(iz0 + 1, 0), DD - 1);

    float acc[CC];
#pragma unroll
    for (int c = 0; c < CC; ++c) acc[c] = 0.f;

    float wyv[2] = {1.f - ty, ty};
    float wxv[2] = {1.f - tx, tx};
    int   ys[2]  = {y0, y1};
    int   xs[2]  = {x0, x1};
    float wz0 = 1.f - tz, wz1 = tz;

    if constexpr (TR) {
        const float* gb = grid + b * (GHH * GWW * DD * CC);
#pragma unroll
        for (int jy = 0; jy < 2; ++jy) {
#pragma unroll
            for (int jx = 0; jx < 2; ++jx) {
                float wsp = wyv[jy] * wxv[jx];
                float w0 = wsp * wz0, w1 = wsp * wz1;
                const float* p = gb + (ys[jy] * GWW + xs[jx]) * (DD * CC);
                const float4* p0 = (const float4*)(p + z0 * CC);  // 16B aligned: 12*z % 4 == 0
                const float4* p1 = (const float4*)(p + z1 * CC);
#pragma unroll
                for (int k = 0; k < 3; ++k) {
                    float4 a = p0[k];
                    float4 q = p1[k];
                    acc[4*k+0] += w0 * a.x + w1 * q.x;
                    acc[4*k+1] += w0 * a.y + w1 * q.y;
                    acc[4*k+2] += w0 * a.z + w1 * q.z;
                    acc[4*k+3] += w0 * a.w + w1 * q.w;
                }
            }
        }
    } else {
        // fallback: original [B][C][D][GH][GW] layout, scalar gathers
        const float* gb = grid + b * (CC * DD * GHH * GWW);
#pragma unroll
        for (int jy = 0; jy < 2; ++jy) {
#pragma unroll
            for (int jx = 0; jx < 2; ++jx) {
                float wsp = wyv[jy] * wxv[jx];
                float w0 = wsp * wz0, w1 = wsp * wz1;
                int sp0 = z0 * (GHH * GWW) + ys[jy] * GWW + xs[jx];
                int sp1 = z1 * (GHH * GWW) + ys[jy] * GWW + xs[jx];
#pragma unroll
                for (int c = 0; c < CC; ++c) {
                    acc[c] += w0 * gb[c * (DD * GHH * GWW) + sp0]
                            + w1 * gb[c * (DD * GHH * GWW) + sp1];
                }
            }
        }
    }

    const float* imgb = image + (size_t)b * 3 * HWP + sp;
    float r  = imgb[0 * HWP];
    float g2 = imgb[1 * HWP];
    float b2 = imgb[2 * HWP];
    float* outb = out + (size_t)b * 3 * HWP + sp;
#pragma unroll
    for (int c = 0; c < 3; ++c) {
        outb[c * HWP] = acc[4*c+0] * r + acc[4*c+1] * g2 + acc[4*c+2] * b2 + acc[4*c+3];
    }
}

extern "C" void kernel_launch(void* const* d_in, const int* in_sizes, int n_in,
                              void* d_out, int out_size, void* d_ws, size_t ws_size,
                              hipStream_t stream) {
    const float* grid  = (const float*)d_in[0];
    const float* guide = (const float*)d_in[1];
    const float* image = (const float*)d_in[2];
    float* out = (float*)d_out;

    const int npix = BB * HWP;
    const int nblk = npix / 256;

    if (ws_size >= (size_t)GRID_N * sizeof(float)) {
        float* tg = (float*)d_ws;
        grid_transpose_k<<<(GRID_N + 255) / 256, 256, 0, stream>>>(grid, tg);
        bilateral_slice_apply_k<true><<<nblk, 256, 0, stream>>>(tg, guide, image, out);
    } else {
        bilateral_slice_apply_k<false><<<nblk, 256, 0, stream>>>(grid, guide, image, out);
    }
}

// Round 2
// 31.181 us; speedup vs baseline: 2.1052x; 2.1052x over previous
//
#include <hip/hip_runtime.h>

// BilateralSliceApply: grid [4,12,8,16,16] f32, guide [4,1024,1024] f32,
// image [4,3,1024,1024] f32 -> out [4,3,1024,1024] f32.
//
// One block per image row: y-lerp the 2 relevant grid rows into LDS once
// (yslab[x][z][c], 16*96 floats, x-stride padded to 100 to spread banks),
// then each thread does 4 pixels with bilinear (x,z) interp from LDS.
// All guide/image/out accesses are float4.

static constexpr int B_ = 4, C_ = 12, D_ = 8, GH_ = 16, GW_ = 16;
static constexpr int H_ = 1024, W_ = 1024;
static constexpr int HW_ = H_ * W_;
static constexpr int XS = D_ * C_ + 4;   // 100 floats: +4 pad rotates banks per x

__global__ __launch_bounds__(256) void bsa_row_kernel(
    const float* __restrict__ grid,   // [B][C][D][GH][GW]
    const float* __restrict__ guide,  // [B][H][W]
    const float* __restrict__ image,  // [B][3][H][W]
    float* __restrict__ out)          // [B][3][H][W]
{
    __shared__ float s[GW_ * XS];     // 1600 floats = 6.4 KB

    const int bid = blockIdx.x;       // = b*H + y
    const int y = bid & (H_ - 1);
    const int b = bid >> 10;
    const int t = threadIdx.x;

    // ---- per-row y interpolation factors ----
    float gyc = (y + 0.5f) * ((float)GH_ / (float)H_) - 0.5f;
    float fy = floorf(gyc);
    float ty = gyc - fy;
    int iy = (int)fy;
    int y0 = min(max(iy, 0), GH_ - 1);
    int y1 = min(max(iy + 1, 0), GH_ - 1);

    // ---- pixel input loads (issue early; latency hides under staging) ----
    const int xp = t << 2;                         // 4 pixels per thread
    const size_t rowoff = ((size_t)b * H_ + y) * W_ + xp;
    float4 gd = *(const float4*)(guide + rowoff);
    const float* imgb = image + ((size_t)b * 3) * HW_ + (size_t)y * W_ + xp;
    float4 ir = *(const float4*)(imgb + 0 * (size_t)HW_);
    float4 ig = *(const float4*)(imgb + 1 * (size_t)HW_);
    float4 ib = *(const float4*)(imgb + 2 * (size_t)HW_);

    // ---- stage y-lerped grid row into LDS: s[x*XS + z*12 + c] ----
    const float* gb = grid + b * (C_ * D_ * GH_ * GW_);
#pragma unroll
    for (int o = t; o < C_ * D_ * GW_; o += 256) {  // 1536 elems, 6 iters
        int x = o & 15;                // o = c*128 + z*16 + x (coalesced reads)
        int z = (o >> 4) & 7;
        int c = o >> 7;
        int base = c * (D_ * GH_ * GW_) + z * (GH_ * GW_);
        float v0 = gb[base + y0 * GW_ + x];
        float v1 = gb[base + y1 * GW_ + x];
        s[x * XS + z * C_ + c] = v0 + ty * (v1 - v0);
    }
    __syncthreads();

    // ---- x cell: shared by all 4 aligned pixels of this thread ----
    // (fx boundary falls at x = 64k+31.5, always BETWEEN aligned 4-groups)
    float gxc = (xp + 0.5f) * ((float)GW_ / (float)W_) - 0.5f;
    float fx = floorf(gxc);
    int ix = (int)fx;
    int x0 = min(max(ix, 0), GW_ - 1);
    int x1 = min(max(ix + 1, 0), GW_ - 1);
    float txb = gxc - fx;

    const float* s0 = s + x0 * XS;
    const float* s1 = s + x1 * XS;

    float gzv[4] = {gd.x, gd.y, gd.z, gd.w};
    float rv[4]  = {ir.x, ir.y, ir.z, ir.w};
    float gv[4]  = {ig.x, ig.y, ig.z, ig.w};
    float bv[4]  = {ib.x, ib.y, ib.z, ib.w};
    float o0[4], o1[4], o2[4];

#pragma unroll
    for (int j = 0; j < 4; ++j) {      // fully unrolled: all indices static
        float tx = txb + j * (1.0f / 64.0f);
        float gz = gzv[j] * (float)D_ - 0.5f;
        float fz = floorf(gz);
        float tz = gz - fz;
        int iz = (int)fz;
        int z0 = min(max(iz, 0), D_ - 1);
        int z1 = min(max(iz + 1, 0), D_ - 1);

        float w00 = (1.f - tx) * (1.f - tz);   // (x0,z0)
        float w01 = (1.f - tx) * tz;           // (x0,z1)
        float w10 = tx * (1.f - tz);           // (x1,z0)
        float w11 = tx * tz;                   // (x1,z1)

        const float* p00 = s0 + z0 * C_;
        const float* p01 = s0 + z1 * C_;
        const float* p10 = s1 + z0 * C_;
        const float* p11 = s1 + z1 * C_;

#pragma unroll
        for (int k = 0; k < 3; ++k) {          // one coeff-quad = one out chan
            float4 a0 = *(const float4*)(p00 + 4 * k);
            float4 a1 = *(const float4*)(p01 + 4 * k);
            float4 a2 = *(const float4*)(p10 + 4 * k);
            float4 a3 = *(const float4*)(p11 + 4 * k);
            float cx = w00 * a0.x + w01 * a1.x + w10 * a2.x + w11 * a3.x;
            float cy = w00 * a0.y + w01 * a1.y + w10 * a2.y + w11 * a3.y;
            float cz = w00 * a0.z + w01 * a1.z + w10 * a2.z + w11 * a3.z;
            float cw = w00 * a0.w + w01 * a1.w + w10 * a2.w + w11 * a3.w;
            float res = cx * rv[j] + cy * gv[j] + cz * bv[j] + cw;
            if (k == 0) o0[j] = res;
            else if (k == 1) o1[j] = res;
            else o2[j] = res;
        }
    }

    float* ob = out + ((size_t)b * 3) * HW_ + (size_t)y * W_ + xp;
    *(float4*)(ob + 0 * (size_t)HW_) = make_float4(o0[0], o0[1], o0[2], o0[3]);
    *(float4*)(ob + 1 * (size_t)HW_) = make_float4(o1[0], o1[1], o1[2], o1[3]);
    *(float4*)(ob + 2 * (size_t)HW_) = make_float4(o2[0], o2[1], o2[2], o2[3]);
}

extern "C" void kernel_launch(void* const* d_in, const int* in_sizes, int n_in,
                              void* d_out, int out_size, void* d_ws, size_t ws_size,
                              hipStream_t stream) {
    const float* grid  = (const float*)d_in[0];
    const float* guide = (const float*)d_in[1];
    const float* image = (const float*)d_in[2];
    float* out = (float*)d_out;

    bsa_row_kernel<<<B_ * H_, 256, 0, stream>>>(grid, guide, image, out);
}